// Round 5
// baseline (986.931 us; speedup 1.0000x reference)
//
#include <hip/hip_runtime.h>
#include <stdint.h>

// GraphVertModel: B=32, M=512, F_N=64, D=128, GS=4, L=8
// Round 5 (= round 4 + fence fix): ONE persistent kernel for the whole net.
// grid=256 blocks (160KB LDS -> 1 block/CU, co-resident), block (b,mt) owns
// 64 rows of sample b for all 8 layers. h in registers, hb in LDS.
// Per layer: stageA (multi=hb@W+b -> global Mh[parity]) -> device-scope
// 8-block/sample spin barrier -> stageB (adjacency GEMM, swizzled 3-buffer
// global_load_lds pipeline, counted vmcnt) -> LDS channel-max -> residual.
// Layer 7 epilogue: Wout projection straight to d_out.
// ws: Gh 64M @0 | Mh0 16M @64M | Mh1 16M @80M | W0T @96M | WlT @96M+64K |
//     flags @98M

#define B_  32
#define M_  512
#define FN_ 64
#define D_  128
#define GS_ 4
#define L_  8

typedef __attribute__((ext_vector_type(8))) short short8;
typedef __attribute__((ext_vector_type(4))) float f32x4;
typedef unsigned short us;

__device__ __forceinline__ us f2bf(float f) {
  union { float f; unsigned int u; } v; v.f = f;
  return (us)((v.u + 0x7FFFu + ((v.u >> 16) & 1u)) >> 16);  // RTNE
}

__device__ __forceinline__ void gl16(const void* g, void* l) {
  __builtin_amdgcn_global_load_lds((const __attribute__((address_space(1))) void*)g,
                                   (__attribute__((address_space(3))) void*)l, 16, 0, 0);
}

// ---- weights: convert + transpose ([g][c][p] -> [g][p][c]) ----------------
__global__ void k_convW(const float* __restrict__ W0, const float* __restrict__ Wl,
                        us* __restrict__ W0T, us* __restrict__ WlT) {
  int i = blockIdx.x * blockDim.x + threadIdx.x;
  const int n0 = GS_ * FN_ * D_;
  if (i < n0) {
    int g = i / (FN_ * D_), r = i % (FN_ * D_), c = r / D_, p = r % D_;
    W0T[((size_t)g * D_ + p) * FN_ + c] = f2bf(W0[i]);
  } else {
    int j = i - n0;
    if (j < 7 * GS_ * D_ * D_) {
      int l = j / (GS_ * D_ * D_), r = j % (GS_ * D_ * D_);
      int g = r / (D_ * D_), r2 = r % (D_ * D_), c = r2 / D_, p = r2 % D_;
      WlT[(((size_t)l * GS_ + g) * D_ + p) * D_ + c] = f2bf(Wl[j]);
    }
  }
}

__global__ void k_init(int* flags) { flags[threadIdx.x] = 0; }

// ---- stage A: multi[g][n(my 64)][p] = hbL @ W + bias -> Mw (transposed) ---
template<int NKA, int CC>
__device__ __forceinline__ void stageA(const us* __restrict__ Wt,
                                       const float* __restrict__ bias,
                                       us* __restrict__ Mw,
                                       const us* hbL, us (*smS)[24576],
                                       int g, int hf, int lr, int kq,
                                       int srow, int scol, int kk, int b, int mt) {
  f32x4 acc[4][4];
#pragma unroll
  for (int i = 0; i < 4; ++i)
#pragma unroll
    for (int j = 0; j < 4; ++j) acc[i][j] = (f32x4){0.f, 0.f, 0.f, 0.f};

#define STGA(bufi, ks) do { \
    us* bb_ = smS[bufi] + g * 6144; \
    _Pragma("unroll") \
    for (int u_ = 0; u_ < 4; ++u_) { \
      const us* sp_ = Wt + (size_t)g * D_ * CC + (size_t)(hf * 64 + u_ * 16 + srow) * CC \
                      + (ks) * 32 + scol; \
      gl16(sp_, bb_ + 2048 + (hf * 4 + u_) * 512); \
    } \
  } while (0)

  STGA(0, 0);
  STGA(1, 1);
  const int cm = (CC == 64) ? 7 : 15;
#pragma unroll
  for (int ks = 0; ks < NKA; ++ks) {
    if (ks < NKA - 1) asm volatile("s_waitcnt vmcnt(4)" ::: "memory");
    else              asm volatile("s_waitcnt vmcnt(0)" ::: "memory");
    __builtin_amdgcn_sched_barrier(0);
    const us* sb = smS[ks % 3] + g * 6144 + 2048;
    short8 af[4], bf[4];
#pragma unroll
    for (int i = 0; i < 4; ++i)
      af[i] = *(const short8*)&hbL[(i * 16 + lr) * 128 + (((ks * 4 + kq) ^ (lr & cm)) << 3)];
#pragma unroll
    for (int j = 0; j < 4; ++j)
      bf[j] = *(const short8*)&sb[(hf * 64 + j * 16 + lr) * 32 + kk];
    if (ks + 2 < NKA) STGA((ks + 2) % 3, ks + 2);
    asm volatile("s_waitcnt lgkmcnt(0)" ::: "memory");
    __builtin_amdgcn_sched_barrier(0);
#pragma unroll
    for (int i = 0; i < 4; ++i)
#pragma unroll
      for (int j = 0; j < 4; ++j)
        acc[i][j] = __builtin_amdgcn_mfma_f32_16x16x32_bf16(af[i], bf[j], acc[i][j], 0, 0, 0);
  }
#undef STGA

#pragma unroll
  for (int j = 0; j < 4; ++j) {
    const int p = hf * 64 + j * 16 + lr;
    const float bv = bias[g * D_ + p];
    us* op = Mw + ((size_t)(b * GS_ + g) * D_ + p) * M_;
#pragma unroll
    for (int i = 0; i < 4; ++i) {
      const int n0 = mt * 64 + i * 16 + kq * 4;
      f32x4 v = acc[i][j];
      ushort4 o;
      o.x = f2bf(v[0] + bv); o.y = f2bf(v[1] + bv);
      o.z = f2bf(v[2] + bv); o.w = f2bf(v[3] + bv);
      *(ushort4*)(op + n0) = o;
    }
  }
}

// ---- the persistent whole-network kernel ----------------------------------
__launch_bounds__(512, 1)
__global__ void k_net(const float* __restrict__ G, const float* __restrict__ x,
                      const us* __restrict__ W0T, const us* __restrict__ WlT,
                      const float* __restrict__ b0, const float* __restrict__ bl,
                      const float* __restrict__ Wout, const float* __restrict__ bout,
                      us* __restrict__ Gh, us* __restrict__ Mh0, us* __restrict__ Mh1,
                      int* flags, float* __restrict__ out) {
  __shared__ __align__(16) us smS[3][24576];  // 144 KB staging / f32 reduction
  __shared__ __align__(16) us hbL[8192];      // 16 KB  [64][128] swizzled bf16 h

  const int bid = blockIdx.x;
  const int swz = (bid & 7) * 32 + (bid >> 3);   // sample-group on one XCD
  const int b = swz >> 3, mt = swz & 7;

  const int t = threadIdx.x;
  const int w = t >> 6, g = w >> 1, hf = w & 1;
  const int lane = t & 63, lr = lane & 15, kq = lane >> 4;
  const int srow = lane >> 2;
  const int scol = ((lane & 3) ^ ((lane >> 3) & 3)) * 8;
  const int kk = (kq ^ ((lr >> 1) & 3)) * 8;
  const int m_l = t >> 3, pq = t & 7;

  // ---- convert my G slice f32 -> bf16 (block-local) ------------------------
  {
    const int segb = t >> 7, col = (t & 127) * 4;
#pragma unroll 4
    for (int it = 0; it < 64; ++it) {
      const int seg = segb + it * 4;            // 0..255 = [g][row]
      const int gg = seg >> 6, rr = seg & 63;
      const size_t rb = ((size_t)(b * GS_ + gg) * M_ + mt * 64 + rr) * M_;
      float4 v = *(const float4*)(G + rb + col);
      ushort4 o;
      o.x = f2bf(v.x); o.y = f2bf(v.y); o.z = f2bf(v.z); o.w = f2bf(v.w);
      *(ushort4*)(Gh + rb + col) = o;
    }
  }
  // ---- convert my x slice into hbL (swizzled, 64 cols used) ----------------
  {
    const int row = t >> 3, c8 = t & 7;
    const float* xs = x + ((size_t)b * M_ + mt * 64 + row) * FN_ + c8 * 8;
    float4 v0 = *(const float4*)xs, v1 = *(const float4*)(xs + 4);
    ushort4 o0, o1;
    o0.x = f2bf(v0.x); o0.y = f2bf(v0.y); o0.z = f2bf(v0.z); o0.w = f2bf(v0.w);
    o1.x = f2bf(v1.x); o1.y = f2bf(v1.y); o1.z = f2bf(v1.z); o1.w = f2bf(v1.w);
    us* dp = hbL + row * 128 + ((c8 ^ (row & 7)) << 3);
    *(ushort4*)dp = o0; *(ushort4*)(dp + 4) = o1;
  }
  __syncthreads();

  f32x4 hreg[4];  // my h: row m_l, cols pq*16 + k*4 .. +3

  for (int l = 0; l < L_; ++l) {
    us* Mw = (l & 1) ? Mh1 : Mh0;

    // ===== stage A =====
    if (l == 0)
      stageA<FN_ / 32, FN_>(W0T, b0, Mw, hbL, smS, g, hf, lr, kq, srow, scol, kk, b, mt);
    else
      stageA<D_ / 32, D_>(WlT + (size_t)(l - 1) * GS_ * D_ * D_,
                          bl + (size_t)(l - 1) * GS_ * D_,
                          Mw, hbL, smS, g, hf, lr, kq, srow, scol, kk, b, mt);

    // ===== inter-block barrier over the 8 blocks of sample b =====
    __builtin_amdgcn_fence(__ATOMIC_RELEASE, "agent");
    __syncthreads();
    if (t == 0) {
      int* fl = flags + l * B_ + b;
      __hip_atomic_fetch_add(fl, 1, __ATOMIC_RELAXED, __HIP_MEMORY_SCOPE_AGENT);
      while (__hip_atomic_load(fl, __ATOMIC_RELAXED, __HIP_MEMORY_SCOPE_AGENT) < 8)
        __builtin_amdgcn_s_sleep(2);
    }
    __syncthreads();
    __builtin_amdgcn_fence(__ATOMIC_ACQUIRE, "agent");

    // ===== stage B: xout = G @ multi over K=512, relu+max fused =====
    {
      const us* AgB = Gh + ((size_t)(b * GS_ + g) * M_ + mt * 64) * M_;
      const us* BgB = Mw + (size_t)(b * GS_ + g) * D_ * M_;
      f32x4 acc[4][4];
#pragma unroll
      for (int i = 0; i < 4; ++i)
#pragma unroll
        for (int j = 0; j < 4; ++j) acc[i][j] = (f32x4){0.f, 0.f, 0.f, 0.f};

#define STGB(bufi, ks) do { \
      us* bb_ = smS[bufi] + g * 6144; \
      _Pragma("unroll") \
      for (int u_ = 0; u_ < 6; ++u_) { \
        const int ls_ = hf * 6 + u_; \
        const us* sp_ = (ls_ < 4) \
          ? AgB + (size_t)(ls_ * 16 + srow) * M_ + (ks) * 32 + scol \
          : BgB + (size_t)((ls_ - 4) * 16 + srow) * M_ + (ks) * 32 + scol; \
        gl16(sp_, bb_ + ls_ * 512 + lane * 8); \
      } \
    } while (0)

      STGB(0, 0);
      STGB(1, 1);
#pragma unroll
      for (int ks = 0; ks < 16; ++ks) {
        if (ks < 15) asm volatile("s_waitcnt vmcnt(6)" ::: "memory");
        else         asm volatile("s_waitcnt vmcnt(0)" ::: "memory");
        __builtin_amdgcn_s_barrier();
        __builtin_amdgcn_sched_barrier(0);
        const us* sa = smS[ks % 3] + g * 6144;
        const us* sb = sa + 2048;
        short8 af[4], bf[4];
#pragma unroll
        for (int i = 0; i < 4; ++i)
          af[i] = *(const short8*)&sa[(i * 16 + lr) * 32 + kk];
#pragma unroll
        for (int j = 0; j < 4; ++j)
          bf[j] = *(const short8*)&sb[(hf * 64 + j * 16 + lr) * 32 + kk];
        if (ks + 2 < 16) STGB((ks + 2) % 3, ks + 2);
        asm volatile("s_waitcnt lgkmcnt(0)" ::: "memory");
        __builtin_amdgcn_sched_barrier(0);
#pragma unroll
        for (int i = 0; i < 4; ++i)
#pragma unroll
          for (int j = 0; j < 4; ++j)
            acc[i][j] = __builtin_amdgcn_mfma_f32_16x16x32_bf16(af[i], bf[j], acc[i][j], 0, 0, 0);
      }
#undef STGB

      __builtin_amdgcn_s_barrier();  // staging done; reuse smS as f32 [4][64][128]
      __builtin_amdgcn_sched_barrier(0);

      {  // write my relu'd tile, swizzled (16B f32-chunk ^= row&7)
        float* red = (float*)smS + (size_t)g * 8192;
#pragma unroll
        for (int i = 0; i < 4; ++i)
#pragma unroll
          for (int j = 0; j < 4; ++j) {
            const int col = hf * 64 + j * 16 + lr;
            const int ch = col >> 2, cw = col & 3;
#pragma unroll
            for (int cc = 0; cc < 4; ++cc) {
              const int row = i * 16 + kq * 4 + cc;
              red[row * 128 + ((ch ^ (row & 7)) << 2) + cw] = fmaxf(acc[i][j][cc], 0.f);
            }
          }
      }
      __builtin_amdgcn_s_barrier();
      __builtin_amdgcn_sched_barrier(0);

      {  // cross-channel max + residual into hreg
        const float* red = (const float*)smS;
        f32x4 vm[4];
#pragma unroll
        for (int k = 0; k < 4; ++k) {
          const int ch = pq * 4 + k;
          const float* rp = red + (size_t)m_l * 128 + ((ch ^ (m_l & 7)) << 2);
          f32x4 v = *(const f32x4*)rp;
#pragma unroll
          for (int gg = 1; gg < 4; ++gg) {
            f32x4 u = *(const f32x4*)(rp + (size_t)gg * 8192);
            v[0] = fmaxf(v[0], u[0]); v[1] = fmaxf(v[1], u[1]);
            v[2] = fmaxf(v[2], u[2]); v[3] = fmaxf(v[3], u[3]);
          }
          vm[k] = v;
        }
        if (l == 0) {
#pragma unroll
          for (int k = 0; k < 4; ++k) hreg[k] = vm[k];
        } else {
#pragma unroll
          for (int k = 0; k < 4; ++k) {
            hreg[k][0] += vm[k][0]; hreg[k][1] += vm[k][1];
            hreg[k][2] += vm[k][2]; hreg[k][3] += vm[k][3];
          }
        }
      }
      __builtin_amdgcn_s_barrier();  // all reads of red done before reuse

      if (l < L_ - 1) {  // write hbL bf16 for next layer's stage A
        us* d0 = hbL + m_l * 128 + (((2 * pq) ^ (m_l & 15)) << 3);
        us* d1 = hbL + m_l * 128 + (((2 * pq + 1) ^ (m_l & 15)) << 3);
        ushort4 o0, o1, o2, o3;
        o0.x = f2bf(hreg[0][0]); o0.y = f2bf(hreg[0][1]); o0.z = f2bf(hreg[0][2]); o0.w = f2bf(hreg[0][3]);
        o1.x = f2bf(hreg[1][0]); o1.y = f2bf(hreg[1][1]); o1.z = f2bf(hreg[1][2]); o1.w = f2bf(hreg[1][3]);
        o2.x = f2bf(hreg[2][0]); o2.y = f2bf(hreg[2][1]); o2.z = f2bf(hreg[2][2]); o2.w = f2bf(hreg[2][3]);
        o3.x = f2bf(hreg[3][0]); o3.y = f2bf(hreg[3][1]); o3.z = f2bf(hreg[3][2]); o3.w = f2bf(hreg[3][3]);
        *(ushort4*)d0 = o0; *(ushort4*)(d0 + 4) = o1;
        *(ushort4*)d1 = o2; *(ushort4*)(d1 + 4) = o3;
        __syncthreads();   // hbL visible to all waves before next stage A
      } else {             // final projection
        float s = 0.f;
#pragma unroll
        for (int k = 0; k < 4; ++k) {
          const float4 wv = *(const float4*)(Wout + pq * 16 + k * 4);
          s += hreg[k][0] * wv.x + hreg[k][1] * wv.y + hreg[k][2] * wv.z + hreg[k][3] * wv.w;
        }
        s += __shfl_xor(s, 1);
        s += __shfl_xor(s, 2);
        s += __shfl_xor(s, 4);
        if (pq == 0) out[(size_t)b * M_ + mt * 64 + m_l] = s + bout[0];
      }
    }
  }
}

extern "C" void kernel_launch(void* const* d_in, const int* in_sizes, int n_in,
                              void* d_out, int out_size, void* d_ws, size_t ws_size,
                              hipStream_t stream) {
  const float* G    = (const float*)d_in[0];
  const float* x    = (const float*)d_in[1];
  const float* W0   = (const float*)d_in[2];
  const float* b0   = (const float*)d_in[3];
  const float* Wl   = (const float*)d_in[4];
  const float* bl   = (const float*)d_in[5];
  const float* Wout = (const float*)d_in[6];
  const float* bout = (const float*)d_in[7];

  char* ws = (char*)d_ws;
  us*   Gh    = (us*)(ws);
  us*   Mh0   = (us*)(ws + 67108864);
  us*   Mh1   = (us*)(ws + 83886080);
  us*   W0T   = (us*)(ws + 100663296);
  us*   WlT   = (us*)(ws + 100663296 + 65536);
  int*  flags = (int*)(ws + 102760448);

  k_convW<<<1920, 256, 0, stream>>>(W0, Wl, W0T, WlT);
  k_init<<<1, 256, 0, stream>>>(flags);
  k_net<<<256, 512, 0, stream>>>(G, x, W0T, WlT, b0, bl, Wout, bout,
                                 Gh, Mh0, Mh1, flags, (float*)d_out);
}

// Round 6
// 273.090 us; speedup vs baseline: 3.6139x; 3.6139x over previous
//
#include <hip/hip_runtime.h>
#include <stdint.h>

// GraphVertModel: B=32, M=512, F_N=64, D=128, GS=4, L=8
// Round 6: multi-kernel skeleton (proven) + stage-A fusion into the epilogue.
// k_convW -> k_pre (G conv + x->LDS + stageA(0) -> Mh0) -> k_fused x8.
// k_fused(l): stage B (Gh @ Mh[l&1], swizzled 3-buf global_load_lds pipeline,
// counted vmcnt) -> relu + channel-max (LDS) -> residual (global f32 h) ->
// epilogue stage A(l+1) (hbL @ W -> Mh[(l+1)&1])  [last layer: Wout proj].
// Kernel boundaries provide the multi producer->consumer sync (no spin bars).
// ws: Gh 64M @0 | Mh0 16M @64M | Mh1 16M @80M | h 8M @96M | W0T @104M |
//     WlT @104M+64K

#define B_  32
#define M_  512
#define FN_ 64
#define D_  128
#define GS_ 4
#define L_  8

typedef __attribute__((ext_vector_type(8))) short short8;
typedef __attribute__((ext_vector_type(4))) float f32x4;
typedef unsigned short us;

__device__ __forceinline__ us f2bf(float f) {
  union { float f; unsigned int u; } v; v.f = f;
  return (us)((v.u + 0x7FFFu + ((v.u >> 16) & 1u)) >> 16);  // RTNE
}

__device__ __forceinline__ void gl16(const void* g, void* l) {
  __builtin_amdgcn_global_load_lds((const __attribute__((address_space(1))) void*)g,
                                   (__attribute__((address_space(3))) void*)l, 16, 0, 0);
}

// ---- weights: convert + transpose ([g][c][p] -> [g][p][c]) ----------------
__global__ void k_convW(const float* __restrict__ W0, const float* __restrict__ Wl,
                        us* __restrict__ W0T, us* __restrict__ WlT) {
  int i = blockIdx.x * blockDim.x + threadIdx.x;
  const int n0 = GS_ * FN_ * D_;
  if (i < n0) {
    int g = i / (FN_ * D_), r = i % (FN_ * D_), c = r / D_, p = r % D_;
    W0T[((size_t)g * D_ + p) * FN_ + c] = f2bf(W0[i]);
  } else {
    int j = i - n0;
    if (j < 7 * GS_ * D_ * D_) {
      int l = j / (GS_ * D_ * D_), r = j % (GS_ * D_ * D_);
      int g = r / (D_ * D_), r2 = r % (D_ * D_), c = r2 / D_, p = r2 % D_;
      WlT[(((size_t)l * GS_ + g) * D_ + p) * D_ + c] = f2bf(Wl[j]);
    }
  }
}

// ---- stage A: multi[g][n(my 64)][p] = hbL @ W + bias -> Mw ([p][n] bf16) --
// wave (g,hf) computes 64n x 64p; wave-private staging of its W half-panel.
template<int NKA, int CC>
__device__ __forceinline__ void stageA(const us* __restrict__ Wt,
                                       const float* __restrict__ bias,
                                       us* __restrict__ Mw,
                                       const us* hbL, us (*smS)[24576],
                                       int g, int hf, int lr, int kq,
                                       int srow, int scol, int kk, int b, int mt) {
  f32x4 acc[4][4];
#pragma unroll
  for (int i = 0; i < 4; ++i)
#pragma unroll
    for (int j = 0; j < 4; ++j) acc[i][j] = (f32x4){0.f, 0.f, 0.f, 0.f};

#define STGA(bufi, ks) do { \
    us* bb_ = smS[bufi] + g * 6144; \
    _Pragma("unroll") \
    for (int u_ = 0; u_ < 4; ++u_) { \
      const us* sp_ = Wt + (size_t)g * D_ * CC + (size_t)(hf * 64 + u_ * 16 + srow) * CC \
                      + (ks) * 32 + scol; \
      gl16(sp_, bb_ + 2048 + (hf * 4 + u_) * 512); \
    } \
  } while (0)

  STGA(0, 0);
  STGA(1, 1);
  const int cm = (CC == 64) ? 7 : 15;
#pragma unroll
  for (int ks = 0; ks < NKA; ++ks) {
    if (ks < NKA - 1) asm volatile("s_waitcnt vmcnt(4)" ::: "memory");
    else              asm volatile("s_waitcnt vmcnt(0)" ::: "memory");
    __builtin_amdgcn_sched_barrier(0);
    const us* sb = smS[ks % 3] + g * 6144 + 2048;
    short8 af[4], bf[4];
#pragma unroll
    for (int i = 0; i < 4; ++i)
      af[i] = *(const short8*)&hbL[(i * 16 + lr) * 128 + (((ks * 4 + kq) ^ (lr & cm)) << 3)];
#pragma unroll
    for (int j = 0; j < 4; ++j)
      bf[j] = *(const short8*)&sb[(hf * 64 + j * 16 + lr) * 32 + kk];
    if (ks + 2 < NKA) STGA((ks + 2) % 3, ks + 2);
    asm volatile("s_waitcnt lgkmcnt(0)" ::: "memory");
    __builtin_amdgcn_sched_barrier(0);
#pragma unroll
    for (int i = 0; i < 4; ++i)
#pragma unroll
      for (int j = 0; j < 4; ++j)
        acc[i][j] = __builtin_amdgcn_mfma_f32_16x16x32_bf16(af[i], bf[j], acc[i][j], 0, 0, 0);
  }
#undef STGA

#pragma unroll
  for (int j = 0; j < 4; ++j) {
    const int p = hf * 64 + j * 16 + lr;
    const float bv = bias[g * D_ + p];
    us* op = Mw + ((size_t)(b * GS_ + g) * D_ + p) * M_;
#pragma unroll
    for (int i = 0; i < 4; ++i) {
      const int n0 = mt * 64 + i * 16 + kq * 4;
      f32x4 v = acc[i][j];
      ushort4 o;
      o.x = f2bf(v[0] + bv); o.y = f2bf(v[1] + bv);
      o.z = f2bf(v[2] + bv); o.w = f2bf(v[3] + bv);
      *(ushort4*)(op + n0) = o;
    }
  }
}

// ---- k_pre: G f32->bf16 (block slice) + x->hbL + stage A(0) -> Mh0 --------
__launch_bounds__(512, 1)
__global__ void k_pre(const float* __restrict__ G, const float* __restrict__ x,
                      const us* __restrict__ W0T, const float* __restrict__ b0,
                      us* __restrict__ Gh, us* __restrict__ Mh0) {
  __shared__ __align__(16) us smS[3][24576];
  __shared__ __align__(16) us hbL[8192];

  const int bid = blockIdx.x;
  const int swz = (bid & 7) * 32 + (bid >> 3);
  const int b = swz >> 3, mt = swz & 7;

  const int t = threadIdx.x;
  const int w = t >> 6, g = w >> 1, hf = w & 1;
  const int lane = t & 63, lr = lane & 15, kq = lane >> 4;
  const int srow = lane >> 2;
  const int scol = ((lane & 3) ^ ((lane >> 3) & 3)) * 8;
  const int kk = (kq ^ ((lr >> 1) & 3)) * 8;

  // G slice f32 -> bf16
  {
    const int segb = t >> 7, col = (t & 127) * 4;
#pragma unroll 4
    for (int it = 0; it < 64; ++it) {
      const int seg = segb + it * 4;            // 0..255 = [g][row]
      const int gg = seg >> 6, rr = seg & 63;
      const size_t rb = ((size_t)(b * GS_ + gg) * M_ + mt * 64 + rr) * M_;
      float4 v = *(const float4*)(G + rb + col);
      ushort4 o;
      o.x = f2bf(v.x); o.y = f2bf(v.y); o.z = f2bf(v.z); o.w = f2bf(v.w);
      *(ushort4*)(Gh + rb + col) = o;
    }
  }
  // x slice -> hbL (swizzled, 64 cols used)
  {
    const int row = t >> 3, c8 = t & 7;
    const float* xs = x + ((size_t)b * M_ + mt * 64 + row) * FN_ + c8 * 8;
    float4 v0 = *(const float4*)xs, v1 = *(const float4*)(xs + 4);
    ushort4 o0, o1;
    o0.x = f2bf(v0.x); o0.y = f2bf(v0.y); o0.z = f2bf(v0.z); o0.w = f2bf(v0.w);
    o1.x = f2bf(v1.x); o1.y = f2bf(v1.y); o1.z = f2bf(v1.z); o1.w = f2bf(v1.w);
    us* dp = hbL + row * 128 + ((c8 ^ (row & 7)) << 3);
    *(ushort4*)dp = o0; *(ushort4*)(dp + 4) = o1;
  }
  __syncthreads();

  stageA<FN_ / 32, FN_>(W0T, b0, Mh0, hbL, smS, g, hf, lr, kq, srow, scol, kk, b, mt);
}

// ---- fused: stage B + relu + channel-max + residual + stage A(l+1) --------
template<int FIRST, int LAST>
__launch_bounds__(512, 1)
__global__ void k_fused(const us* __restrict__ Gh, const us* __restrict__ Min,
                        us* __restrict__ Mout,
                        const us* __restrict__ WT, const float* __restrict__ bias,
                        float* __restrict__ h,
                        const float* __restrict__ Wout, const float* __restrict__ bout,
                        float* __restrict__ out) {
  __shared__ __align__(16) us smS[3][24576];  // 144 KB
  __shared__ __align__(16) us hbL[8192];      // 16 KB

  const int bid = blockIdx.x;
  const int swz = (bid & 7) * 32 + (bid >> 3);   // same-b blocks share an XCD
  const int b = swz >> 3, mt = swz & 7;

  const int t = threadIdx.x;
  const int w = t >> 6, g = w >> 1, hf = w & 1;
  const int lane = t & 63, lr = lane & 15, kq = lane >> 4;
  const int srow = lane >> 2;
  const int scol = ((lane & 3) ^ ((lane >> 3) & 3)) * 8;
  const int kk = (kq ^ ((lr >> 1) & 3)) * 8;
  const int m_l = t >> 3, pq = t & 7;

  // ===== stage B: xout = G @ multi over K=512 =====
  const us* AgB = Gh + ((size_t)(b * GS_ + g) * M_ + mt * 64) * M_;
  const us* BgB = Min + (size_t)(b * GS_ + g) * D_ * M_;
  f32x4 acc[4][4];
#pragma unroll
  for (int i = 0; i < 4; ++i)
#pragma unroll
    for (int j = 0; j < 4; ++j) acc[i][j] = (f32x4){0.f, 0.f, 0.f, 0.f};

#define STGB(bufi, ks) do { \
    us* bb_ = smS[bufi] + g * 6144; \
    _Pragma("unroll") \
    for (int u_ = 0; u_ < 6; ++u_) { \
      const int ls_ = hf * 6 + u_; \
      const us* sp_ = (ls_ < 4) \
        ? AgB + (size_t)(ls_ * 16 + srow) * M_ + (ks) * 32 + scol \
        : BgB + (size_t)((ls_ - 4) * 16 + srow) * M_ + (ks) * 32 + scol; \
      gl16(sp_, bb_ + ls_ * 512 + lane * 8); \
    } \
  } while (0)

  STGB(0, 0);
  STGB(1, 1);
#pragma unroll
  for (int ks = 0; ks < 16; ++ks) {
    if (ks < 15) asm volatile("s_waitcnt vmcnt(6)" ::: "memory");
    else         asm volatile("s_waitcnt vmcnt(0)" ::: "memory");
    __builtin_amdgcn_s_barrier();
    __builtin_amdgcn_sched_barrier(0);
    const us* sa = smS[ks % 3] + g * 6144;
    const us* sb = sa + 2048;
    short8 af[4], bf[4];
#pragma unroll
    for (int i = 0; i < 4; ++i)
      af[i] = *(const short8*)&sa[(i * 16 + lr) * 32 + kk];
#pragma unroll
    for (int j = 0; j < 4; ++j)
      bf[j] = *(const short8*)&sb[(hf * 64 + j * 16 + lr) * 32 + kk];
    if (ks + 2 < 16) STGB((ks + 2) % 3, ks + 2);
    asm volatile("s_waitcnt lgkmcnt(0)" ::: "memory");
    __builtin_amdgcn_sched_barrier(0);
#pragma unroll
    for (int i = 0; i < 4; ++i)
#pragma unroll
      for (int j = 0; j < 4; ++j)
        acc[i][j] = __builtin_amdgcn_mfma_f32_16x16x32_bf16(af[i], bf[j], acc[i][j], 0, 0, 0);
  }
#undef STGB

  __builtin_amdgcn_s_barrier();  // staging done; reuse smS as f32 [4][64][128]
  __builtin_amdgcn_sched_barrier(0);

  {  // write my relu'd tile, swizzled (16B f32-chunk ^= row&7)
    float* red = (float*)smS + (size_t)g * 8192;
#pragma unroll
    for (int i = 0; i < 4; ++i)
#pragma unroll
      for (int j = 0; j < 4; ++j) {
        const int col = hf * 64 + j * 16 + lr;
        const int ch = col >> 2, cw = col & 3;
#pragma unroll
        for (int cc = 0; cc < 4; ++cc) {
          const int row = i * 16 + kq * 4 + cc;
          red[row * 128 + ((ch ^ (row & 7)) << 2) + cw] = fmaxf(acc[i][j][cc], 0.f);
        }
      }
  }
  __builtin_amdgcn_s_barrier();
  __builtin_amdgcn_sched_barrier(0);

  // cross-channel max + residual
  f32x4 hreg[4];
  {
    const float* red = (const float*)smS;
#pragma unroll
    for (int k = 0; k < 4; ++k) {
      const int ch = pq * 4 + k;
      const float* rp = red + (size_t)m_l * 128 + ((ch ^ (m_l & 7)) << 2);
      f32x4 v = *(const f32x4*)rp;
#pragma unroll
      for (int gg = 1; gg < 4; ++gg) {
        f32x4 u = *(const f32x4*)(rp + (size_t)gg * 8192);
        v[0] = fmaxf(v[0], u[0]); v[1] = fmaxf(v[1], u[1]);
        v[2] = fmaxf(v[2], u[2]); v[3] = fmaxf(v[3], u[3]);
      }
      hreg[k] = v;
    }
  }
  const size_t ho = ((size_t)b * M_ + mt * 64 + m_l) * D_ + pq * 16;
  float4* hp = (float4*)(h + ho);
  if (!FIRST) {
#pragma unroll
    for (int k = 0; k < 4; ++k) {
      float4 hv = hp[k];
      hreg[k][0] += hv.x; hreg[k][1] += hv.y; hreg[k][2] += hv.z; hreg[k][3] += hv.w;
    }
  }

  if constexpr (!LAST) {
    // write h (f32, residual stream) + hbL (bf16, swizzled) for stage A
#pragma unroll
    for (int k = 0; k < 4; ++k)
      hp[k] = (float4){hreg[k][0], hreg[k][1], hreg[k][2], hreg[k][3]};
    us* d0 = hbL + m_l * 128 + (((2 * pq) ^ (m_l & 15)) << 3);
    us* d1 = hbL + m_l * 128 + (((2 * pq + 1) ^ (m_l & 15)) << 3);
    ushort4 o0, o1, o2, o3;
    o0.x = f2bf(hreg[0][0]); o0.y = f2bf(hreg[0][1]); o0.z = f2bf(hreg[0][2]); o0.w = f2bf(hreg[0][3]);
    o1.x = f2bf(hreg[1][0]); o1.y = f2bf(hreg[1][1]); o1.z = f2bf(hreg[1][2]); o1.w = f2bf(hreg[1][3]);
    o2.x = f2bf(hreg[2][0]); o2.y = f2bf(hreg[2][1]); o2.z = f2bf(hreg[2][2]); o2.w = f2bf(hreg[2][3]);
    o3.x = f2bf(hreg[3][0]); o3.y = f2bf(hreg[3][1]); o3.z = f2bf(hreg[3][2]); o3.w = f2bf(hreg[3][3]);
    *(ushort4*)d0 = o0; *(ushort4*)(d0 + 4) = o1;
    *(ushort4*)d1 = o2; *(ushort4*)(d1 + 4) = o3;
    __syncthreads();  // hbL + smS reuse safe for all waves

    // ===== stage A(l+1): multi = hbL @ W + b -> Mout =====
    stageA<D_ / 32, D_>(WT, bias, Mout, hbL, smS, g, hf, lr, kq, srow, scol, kk, b, mt);
  } else {
    // final projection
    float s = 0.f;
#pragma unroll
    for (int k = 0; k < 4; ++k) {
      const float4 wv = *(const float4*)(Wout + pq * 16 + k * 4);
      s += hreg[k][0] * wv.x + hreg[k][1] * wv.y + hreg[k][2] * wv.z + hreg[k][3] * wv.w;
    }
    s += __shfl_xor(s, 1);
    s += __shfl_xor(s, 2);
    s += __shfl_xor(s, 4);
    if (pq == 0) out[(size_t)b * M_ + mt * 64 + m_l] = s + bout[0];
  }
}

extern "C" void kernel_launch(void* const* d_in, const int* in_sizes, int n_in,
                              void* d_out, int out_size, void* d_ws, size_t ws_size,
                              hipStream_t stream) {
  const float* G    = (const float*)d_in[0];
  const float* x    = (const float*)d_in[1];
  const float* W0   = (const float*)d_in[2];
  const float* b0   = (const float*)d_in[3];
  const float* Wl   = (const float*)d_in[4];
  const float* bl   = (const float*)d_in[5];
  const float* Wout = (const float*)d_in[6];
  const float* bout = (const float*)d_in[7];

  char* ws = (char*)d_ws;
  us*   Gh  = (us*)(ws);
  us*   Mh0 = (us*)(ws + 67108864);
  us*   Mh1 = (us*)(ws + 83886080);
  float* h  = (float*)(ws + 100663296);
  us*   W0T = (us*)(ws + 109051904);
  us*   WlT = (us*)(ws + 109051904 + 65536);
  float* out = (float*)d_out;

  k_convW<<<1920, 256, 0, stream>>>(W0, Wl, W0T, WlT);
  k_pre<<<256, 512, 0, stream>>>(G, x, W0T, b0, Gh, Mh0);

  // fused(l): stage B reads Mh[l&1]; stage A writes Mh[(l+1)&1] with Wl[l]
  k_fused<1, 0><<<256, 512, 0, stream>>>(Gh, Mh0, Mh1,
      WlT + (size_t)0 * GS_ * D_ * D_, bl + (size_t)0 * GS_ * D_,
      h, Wout, bout, out);
  for (int l = 1; l < L_ - 1; ++l) {
    const us* Min = (l & 1) ? Mh1 : Mh0;
    us* Mout      = (l & 1) ? Mh0 : Mh1;
    k_fused<0, 0><<<256, 512, 0, stream>>>(Gh, Min, Mout,
        WlT + (size_t)l * GS_ * D_ * D_, bl + (size_t)l * GS_ * D_,
        h, Wout, bout, out);
  }
  k_fused<0, 1><<<256, 512, 0, stream>>>(Gh, (L_ - 1) & 1 ? Mh1 : Mh0, nullptr,
      nullptr, nullptr, h, Wout, bout, out);
}